// Round 7
// baseline (441.254 us; speedup 1.0000x reference)
//
#include <hip/hip_runtime.h>
#include <math.h>

// Problem constants
#define T_DIM 16
#define B_DIM 128
#define N_DIM 2048
#define TB    (T_DIM * B_DIM)   // 2048 rows of the GEMM

// Workspace layout (bytes). h is f32 (16MB used of 32MB reserved).
#define WS_H      0
#define WS_PSUM   35651584      // [32][2048] f64 per-rowband col sums
#define WS_PSUM2  36175872      // [32][2048] f64 per-rowband col sq-sums
#define WS_SSUM   36700160      // [2][2048] f64 row-sum parts (per wave)

typedef __attribute__((ext_vector_type(4))) double d4;

// ---- MFMA f64 wiring probe helpers ----------------------------------------
__device__ __forceinline__ double probeA(int m, int k) {
    return (double)((m * 7 + k * 13) % 23 - 11);
}
__device__ __forceinline__ double probeB(int k, int n) {
    return (double)((k * 5 + n * 3) % 19 - 9);
}

// In-kernel probe: every block derives the MFMA wiring hypothesis itself.
// Hypothesis encoding fh = ab*4 + dF;  ab = aF + 2*bF.
//  A-form 0: m=l&15,k=l>>4   1: m=l>>2,k=l&3
//  B-form 0: n=l&15,k=l>>4   1: n=l>>2,k=l&3
//  D-form 0: i=4*(l>>4)+r,j=l&15   1: i=(l>>4)+4r,j=l&15
//         2: j=4*(l>>4)+r,i=l&15   3: j=(l>>4)+4r,i=l&15
__device__ unsigned int run_probe(double* Cref, int l) {
    int i0 = l >> 2, j0 = (l & 3) << 2;
    for (int jj = 0; jj < 4; ++jj) {
        double s = 0.0;
        for (int k = 0; k < 4; ++k) s += probeA(i0, k) * probeB(k, j0 + jj);
        Cref[i0 * 16 + j0 + jj] = s;
    }
    __syncthreads();
    unsigned int win = 0xFFFFFFFFu;
    for (int ab = 0; ab < 4; ++ab) {
        int aF = ab & 1, bF = (ab >> 1) & 1;
        int mA = aF ? (l >> 2) : (l & 15);
        int kA = aF ? (l & 3)  : (l >> 4);
        int nB = bF ? (l >> 2) : (l & 15);
        int kB = bF ? (l & 3)  : (l >> 4);
        d4 d = (d4)0.0;
        d = __builtin_amdgcn_mfma_f64_16x16x4f64(probeA(mA, kA), probeB(kB, nB), d, 0, 0, 0);
        for (int dF = 0; dF < 4; ++dF) {
            double err = 0.0;
            for (int r = 0; r < 4; ++r) {
                int ii, jj;
                if (dF == 0)      { ii = 4 * (l >> 4) + r; jj = l & 15; }
                else if (dF == 1) { ii = (l >> 4) + 4 * r; jj = l & 15; }
                else if (dF == 2) { jj = 4 * (l >> 4) + r; ii = l & 15; }
                else              { jj = (l >> 4) + 4 * r; ii = l & 15; }
                err = fmax(err, fabs(d[r] - Cref[ii * 16 + jj]));
            }
            for (int off = 1; off < 64; off <<= 1)
                err = fmax(err, __shfl_xor(err, off, 64));
            if (err < 1e-9 && win == 0xFFFFFFFFu)
                win = (unsigned)(ab * 4 + dF);
        }
    }
    return win;
}

// ---- GEMM h[row,m] = sum_n x[row,n] * W[m,n] ------------------------------
// v17: 64x32 tile, 2-wave split-K, ZERO loop barriers (R4's winning trait),
// 3 waves/SIMD (R4 was register-bound to 2: 128 VGPR + 128 AGPR acc).
//  - acc shrinks to d4[4][2] = 64 unified regs -> ~130 total, cap 170 via
//    __launch_bounds__(128,3).
//  - zero-pad swizzled staging (LDS 40KB->24KB, 6 blocks/CU resident):
//    A elem (k,m) at word k*64 + ((m+16*(k&3))&63); B elem (k,n) at
//    k*32 + ((n+8*(k&3))&31). Enumerated: stage writes and fragment reads
//    are exactly 2 lanes/bank (free) for all probe wiring forms.
//  - rsum exchange via global ssum[2][2048] parts (frees rbuf; exact f64).
// Theory: with 3 waves/SIMD, one wave's staging/lgkm gap (~600cy) is covered
// by two other waves' MFMA streams (8192cy) -> MfmaUtil 77 -> ~86%.
#define BK 16

#define LOADT(koff)                                                 \
    {                                                               \
        const float* ap = Ag + (koff);                              \
        const float* bp = Bg + (koff);                              \
        sa[0] = *(const float4*)(ap);                               \
        sa[1] = *(const float4*)(ap + 4);                           \
        sa[2] = *(const float4*)(ap + 8);                           \
        sa[3] = *(const float4*)(ap + 12);                          \
        sb[0] = *(const float4*)(bp);                               \
        sb[1] = *(const float4*)(bp + 4);                           \
    }

// A: lane stages its row (m=lane), k=4j+c  -> word (4j+c)*64 + ((lane+16c)&63)
// B: lane stages n=lane&31, k=8*(lane>>5)+4jB+cB
#define STAGE(Ab, Bb)                                               \
    _Pragma("unroll")                                               \
    for (int j = 0; j < 4; ++j) {                                   \
        (Ab)[(4 * j + 0) * 64 + swA0] = sa[j].x;                    \
        (Ab)[(4 * j + 1) * 64 + swA1] = sa[j].y;                    \
        (Ab)[(4 * j + 2) * 64 + swA2] = sa[j].z;                    \
        (Ab)[(4 * j + 3) * 64 + swA3] = sa[j].w;                    \
    }                                                               \
    _Pragma("unroll")                                               \
    for (int j = 0; j < 2; ++j) {                                   \
        (Bb)[(bk0 + 4 * j + 0) * 32 + swB0] = sb[j].x;              \
        (Bb)[(bk0 + 4 * j + 1) * 32 + swB1] = sb[j].y;              \
        (Bb)[(bk0 + 4 * j + 2) * 32 + swB2] = sb[j].z;              \
        (Bb)[(bk0 + 4 * j + 3) * 32 + swB3] = sb[j].w;              \
    }                                                               \
    if (do_rsum) {                                                  \
        _Pragma("unroll")                                           \
        for (int j = 0; j < 4; ++j)                                 \
            rsum += (double)sa[j].x + (double)sa[j].y +             \
                    (double)sa[j].z + (double)sa[j].w;              \
    }

#define MFMA_COMPUTE(Ab, Bb)                                        \
    _Pragma("unroll")                                               \
    for (int jq = 0; jq < 4; ++jq) {                                \
        double av[4], bv[2];                                        \
        _Pragma("unroll")                                           \
        for (int f = 0; f < 4; ++f)                                 \
            av[f] = (double)(Ab)[jq * 256 + kA * 64 + aoffc[f]];    \
        _Pragma("unroll")                                           \
        for (int g = 0; g < 2; ++g)                                 \
            bv[g] = (double)(Bb)[jq * 128 + kB * 32 + boffc[g]];    \
        _Pragma("unroll")                                           \
        for (int f = 0; f < 4; ++f)                                 \
            _Pragma("unroll")                                       \
            for (int g = 0; g < 2; ++g)                             \
                acc[f][g] = __builtin_amdgcn_mfma_f64_16x16x4f64(   \
                    av[f], bv[g], acc[f][g], 0, 0, 0);              \
    }

__global__ __launch_bounds__(128, 3)
void gemm_hybrid(const float* __restrict__ A, const float* __restrict__ Bw,
                 float* __restrict__ C, double* __restrict__ psum,
                 double* __restrict__ psum2, double* __restrict__ ssum_out) {
    __shared__ __align__(16) char smem[24576];  // 2 waves x 12KB staging; cbuf 16KB
    const int t    = threadIdx.x;
    const int lane = t & 63;
    const int w    = t >> 6;
    const int row0 = blockIdx.y * 64;
    const int col0 = blockIdx.x * 32;
    const int band = blockIdx.y;
    const bool do_rsum = (blockIdx.x == 0);

    // in-block probe (uses cbuf region; dead before staging starts)
    const unsigned int fh = run_probe((double*)smem, lane);
    __syncthreads();

    const float* Ag = A  + (size_t)(row0 + lane) * N_DIM;
    const float* Bg = Bw + (size_t)(col0 + (lane & 31)) * N_DIM + 8 * (lane >> 5);
    const int kw = w * BK;
    double* cbuf = (double*)smem;               // 2048 doubles = 16KB
    double rsum = 0.0;

    // staging swizzle constants
    const int swA0 = lane;
    const int swA1 = (lane + 16) & 63;
    const int swA2 = (lane + 32) & 63;
    const int swA3 = (lane + 48) & 63;
    const int bl   = lane & 31;
    const int bk0  = 8 * (lane >> 5);
    const int swB0 = bl;
    const int swB1 = (bl + 8) & 31;
    const int swB2 = (bl + 16) & 31;
    const int swB3 = (bl + 24) & 31;

    // per-wave staging regions (floats): [A0 1024][B0 512][A1 1024][B1 512]
    float* A0 = (float*)(smem + (size_t)w * 12288);
    float* B0 = A0 + 1024;
    float* A1 = A0 + 1536;
    float* B1 = A0 + 2560;

    float4 sa[4], sb[2];

    if (fh <= 15u) {
        // ================= MFMA path =================
        const int dF = fh & 3, ab = fh >> 2;
        const int aF = ab & 1, bF = (ab >> 1) & 1;
        const int mA = aF ? (lane >> 2) : (lane & 15);
        const int kA = aF ? (lane & 3)  : (lane >> 4);
        const int nB = bF ? (lane >> 2) : (lane & 15);
        const int kB = bF ? (lane & 3)  : (lane >> 4);
        int aoffc[4], boffc[2];
#pragma unroll
        for (int f = 0; f < 4; ++f) aoffc[f] = (16 * f + mA + 16 * kA) & 63;
#pragma unroll
        for (int g = 0; g < 2; ++g) boffc[g] = (16 * g + nB + 8 * kB) & 31;
        int iD[4], jD[4];
#pragma unroll
        for (int r = 0; r < 4; ++r) {
            if (dF == 0)      { iD[r] = 4 * (lane >> 4) + r; jD[r] = lane & 15; }
            else if (dF == 1) { iD[r] = (lane >> 4) + 4 * r; jD[r] = lane & 15; }
            else if (dF == 2) { jD[r] = 4 * (lane >> 4) + r; iD[r] = lane & 15; }
            else              { jD[r] = (lane >> 4) + 4 * r; iD[r] = lane & 15; }
        }

        d4 acc[4][2];
#pragma unroll
        for (int f = 0; f < 4; ++f)
#pragma unroll
            for (int g = 0; g < 2; ++g) acc[f][g] = (d4)0.0;

        LOADT(kw)                 // tile 0
        STAGE(A0, B0)             // -> buf0
        LOADT(kw + 32)            // tile 1

        for (int k0 = kw; k0 < N_DIM; k0 += 64) {
            STAGE(A1, B1)         // tile k0+32 -> buf1
            if (k0 + 64 < N_DIM) { LOADT(k0 + 64) }
            MFMA_COMPUTE(A0, B0)  // tile k0
            if (k0 + 64 < N_DIM) {
                STAGE(A0, B0)     // tile k0+64 -> buf0
                if (k0 + 96 < N_DIM) { LOADT(k0 + 96) }
            }
            MFMA_COMPUTE(A1, B1)  // tile k0+32
        }

        if (do_rsum) ssum_out[w * 2048 + row0 + lane] = rsum;

        __syncthreads();
        if (w == 1) {
#pragma unroll
            for (int f = 0; f < 4; ++f)
#pragma unroll
                for (int g = 0; g < 2; ++g)
#pragma unroll
                    for (int r = 0; r < 4; ++r)
                        cbuf[((f * 2 + g) * 4 + r) * 64 + lane] = acc[f][g][r];
        }
        __syncthreads();
        if (w == 0) {
#pragma unroll
            for (int f = 0; f < 4; ++f)
#pragma unroll
                for (int g = 0; g < 2; ++g)
#pragma unroll
                    for (int r = 0; r < 4; ++r)
                        acc[f][g][r] += cbuf[((f * 2 + g) * 4 + r) * 64 + lane];
            // store C (f32)
#pragma unroll
            for (int f = 0; f < 4; ++f)
#pragma unroll
                for (int r = 0; r < 4; ++r) {
                    int row = row0 + 16 * f + iD[r];
                    float* Crow = C + (size_t)row * N_DIM + col0 + jD[r];
#pragma unroll
                    for (int g = 0; g < 2; ++g)
                        Crow[16 * g] = (float)acc[f][g][r];
                }
            // layout-agnostic BN scatter -> cbuf[row][col] (64x32)
#pragma unroll
            for (int f = 0; f < 4; ++f)
#pragma unroll
                for (int r = 0; r < 4; ++r)
#pragma unroll
                    for (int g = 0; g < 2; ++g)
                        cbuf[(16 * f + iD[r]) * 32 + 16 * g + jD[r]] = acc[f][g][r];
        }
    } else {
        // ================= f64 VALU fallback (probe-fail only; correctness) ====
        double accv[32];
#pragma unroll
        for (int j = 0; j < 32; ++j) accv[j] = 0.0;

        LOADT(kw)
        STAGE(A0, B0)
        LOADT(kw + 32)

        for (int k0 = kw; k0 < N_DIM; k0 += 64) {
            STAGE(A1, B1)
            if (k0 + 64 < N_DIM) { LOADT(k0 + 64) }
#pragma unroll
            for (int k = 0; k < BK; ++k) {
                double a = (double)A0[k * 64 + ((lane + 16 * (k & 3)) & 63)];
#pragma unroll
                for (int j = 0; j < 32; ++j)
                    accv[j] = fma(a, (double)B0[k * 32 + ((j + 8 * (k & 3)) & 31)], accv[j]);
            }
            if (k0 + 64 < N_DIM) {
                STAGE(A0, B0)
                if (k0 + 96 < N_DIM) { LOADT(k0 + 96) }
            }
#pragma unroll
            for (int k = 0; k < BK; ++k) {
                double a = (double)A1[k * 64 + ((lane + 16 * (k & 3)) & 63)];
#pragma unroll
                for (int j = 0; j < 32; ++j)
                    accv[j] = fma(a, (double)B1[k * 32 + ((j + 8 * (k & 3)) & 31)], accv[j]);
            }
        }

        if (do_rsum) ssum_out[w * 2048 + row0 + lane] = rsum;

        __syncthreads();
        if (w == 1) {
#pragma unroll
            for (int j = 0; j < 32; ++j)
                cbuf[j * 64 + lane] = accv[j];
        }
        __syncthreads();
        if (w == 0) {
#pragma unroll
            for (int j = 0; j < 32; ++j) {
                accv[j] += cbuf[j * 64 + lane];
                C[(size_t)(row0 + lane) * N_DIM + col0 + j] = (float)accv[j];
            }
#pragma unroll
            for (int j = 0; j < 32; ++j)
                cbuf[lane * 32 + j] = accv[j];
        }
    }

    // common BN-partial epilogue: cbuf holds h-tile [64][32] (written by w0)
    if (w == 0) {
        const int c = lane & 31, half = lane >> 5;
        double s = 0.0, q = 0.0;
#pragma unroll
        for (int r = 0; r < 32; ++r) {
            double v = cbuf[(32 * half + r) * 32 + c];
            s += v;
            q = fma(v, v, q);
        }
        s += __shfl_xor(s, 32, 64);
        q += __shfl_xor(q, 32, 64);
        if (lane < 32) {
            psum [band * N_DIM + col0 + lane] = s;
            psum2[band * N_DIM + col0 + lane] = q;
        }
    }
}

// ---- fused BN-final + BN-apply + temporal-sum + triple LIF + output -------
__global__ __launch_bounds__(256)
void fused_lif_kernel(const float* __restrict__ x, const float* __restrict__ h,
                      const double* __restrict__ psum, const double* __restrict__ psum2,
                      const float* __restrict__ gamma, const float* __restrict__ beta,
                      const double* __restrict__ ssum, float* __restrict__ out) {
    int idx = blockIdx.x * 256 + threadIdx.x;
    int n = idx & (N_DIM - 1);
    int b = idx >> 11;
    // BN scale/shift for this column
    double s = 0.0, s2 = 0.0;
#pragma unroll
    for (int c = 0; c < 32; ++c) {
        s  += psum [c * N_DIM + n];
        s2 += psum2[c * N_DIM + n];
    }
    double mean = s * (1.0 / 2048.0);
    double var  = s2 * (1.0 / 2048.0) - mean * mean;
    double istd = 1.0 / sqrt(var + 1e-5);
    double sc = istd * (double)gamma[n];
    double sh = (double)beta[n] - mean * sc;
    // temporal sum (ascending t, f64)
    float xv[T_DIM];
    double ts = 0.0;
#pragma unroll
    for (int t = 0; t < T_DIM; ++t) {
        xv[t] = x[(size_t)(t * B_DIM + b) * N_DIM + n];
        ts += (double)xv[t];
    }
    double v1 = 0.0, v2 = 0.0, v3 = 0.0;
#pragma unroll
    for (int t = 0; t < T_DIM; ++t) {
        size_t off = (size_t)(t * B_DIM + b) * N_DIM + n;
        double hv = fma((double)h[off], sc, sh);
        v1 = v1 * 0.5 + hv;
        bool s1 = (v1 >= 1.0); if (s1) v1 = 0.0;
        double in2 = s1 ? (ssum[t * B_DIM + b] + ssum[2048 + t * B_DIM + b]) : 0.0;
        v2 = v2 * 0.5 + in2;
        bool s2b = (v2 >= 1.0); if (s2b) v2 = 0.0;
        double in3 = s1 ? ts : 0.0;
        v3 = v3 * 0.5 + in3;
        bool s3 = (v3 >= 1.0); if (s3) v3 = 0.0;
        out[off] = xv[t] + ((s2b && s3) ? 1.0f : 0.0f);
    }
}

extern "C" void kernel_launch(void* const* d_in, const int* in_sizes, int n_in,
                              void* d_out, int out_size, void* d_ws, size_t ws_size,
                              hipStream_t stream) {
    const float* x     = (const float*)d_in[0];   // [16,128,2048]
    const float* W     = (const float*)d_in[1];   // [2048,2048]
    const float* gamma = (const float*)d_in[2];   // [2048]
    const float* beta  = (const float*)d_in[3];   // [2048]
    float* out = (float*)d_out;

    char* ws = (char*)d_ws;
    float*  h     = (float*)(ws + WS_H);
    double* psum  = (double*)(ws + WS_PSUM);
    double* psum2 = (double*)(ws + WS_PSUM2);
    double* ssum  = (double*)(ws + WS_SSUM);    // [2][2048]

    gemm_hybrid<<<dim3(N_DIM / 32, TB / 64), 128, 0, stream>>>(x, W, h, psum, psum2, ssum);
    fused_lif_kernel<<<(B_DIM * N_DIM) / 256, 256, 0, stream>>>(
        x, h, psum, psum2, gamma, beta, ssum, out);
}

// Round 8
// 313.708 us; speedup vs baseline: 1.4066x; 1.4066x over previous
//
#include <hip/hip_runtime.h>
#include <math.h>

// Problem constants
#define T_DIM 16
#define B_DIM 128
#define N_DIM 2048
#define TB    (T_DIM * B_DIM)   // 2048 rows of the GEMM

// d_ws layout (bytes): h f32 16MB | psum 0.5MB | psum2 0.5MB | ssum 16KB
#define WS_H      0
#define WS_PSUM   16777216
#define WS_PSUM2  17301504
#define WS_SSUM   17825792

typedef __attribute__((ext_vector_type(8))) short short8;
typedef __attribute__((ext_vector_type(4))) float f32x4;

// bf16 split planes: [x0,x1,x2,W0,W1,W2], each [2048][2048] bf16 = 8MB.
// Static device global (module-load allocation; not hipMalloc -> graph-safe).
#define PLANE 4194304ull
__device__ __align__(16) unsigned short g_planes[6ull * PLANE];

// ---- probe helpers (asymmetric integer patterns, exact in bf16/f32) -------
__device__ __forceinline__ double probeA(int m, int k) {
    return (double)((m * 7 + k * 13) % 23 - 11);
}
__device__ __forceinline__ double probeB(int k, int n) {
    return (double)((k * 5 + n * 3) % 19 - 9);
}

// round-to-nearest-even f32 -> bf16; returns bits, writes back-converted f32
__device__ __forceinline__ unsigned bf16_rne(float f, float* back) {
    unsigned u = __float_as_uint(f);
    unsigned r = u + 0x7FFFu + ((u >> 16) & 1u);
    unsigned h = r >> 16;
    *back = __uint_as_float(h << 16);
    return h;
}

// ---- split kernel: f32 -> 3x bf16 planes for x and W, + exact ssum --------
// one block per source row (4096 rows total: x then W); thread = one k-octet.
__global__ __launch_bounds__(256)
void split_kernel(const float* __restrict__ x, const float* __restrict__ W,
                  double* __restrict__ ssum) {
    const int row = blockIdx.x;
    const int tid = threadIdx.x;
    const int mat = row >> 11;          // 0 = x, 1 = W
    const int r   = row & 2047;
    const float* src = (mat ? W : x) + (size_t)r * N_DIM;
    unsigned short* p0 = g_planes + (size_t)(3 * mat) * PLANE
                       + (size_t)r * N_DIM + tid * 8;

    float4 f0 = *(const float4*)(src + tid * 8);
    float4 f1 = *(const float4*)(src + tid * 8 + 4);
    float v[8] = {f0.x, f0.y, f0.z, f0.w, f1.x, f1.y, f1.z, f1.w};
    unsigned h0[8], h1[8], h2[8];
    double s = 0.0;
#pragma unroll
    for (int e = 0; e < 8; ++e) {
        float b;
        h0[e] = bf16_rne(v[e], &b); float r1 = v[e] - b;   // exact residuals
        h1[e] = bf16_rne(r1, &b);   float r2 = r1 - b;
        h2[e] = bf16_rne(r2, &b);
        s += (double)v[e];
    }
    uint4 u;
    u.x = h0[0] | (h0[1] << 16); u.y = h0[2] | (h0[3] << 16);
    u.z = h0[4] | (h0[5] << 16); u.w = h0[6] | (h0[7] << 16);
    *(uint4*)(p0) = u;
    u.x = h1[0] | (h1[1] << 16); u.y = h1[2] | (h1[3] << 16);
    u.z = h1[4] | (h1[5] << 16); u.w = h1[6] | (h1[7] << 16);
    *(uint4*)(p0 + PLANE) = u;
    u.x = h2[0] | (h2[1] << 16); u.y = h2[2] | (h2[3] << 16);
    u.z = h2[4] | (h2[5] << 16); u.w = h2[6] | (h2[7] << 16);
    *(uint4*)(p0 + 2 * PLANE) = u;

    if (mat == 0) {   // spatial row sum (exact f64, fixed order)
        for (int off = 32; off > 0; off >>= 1) s += __shfl_down(s, off, 64);
        __shared__ double wsum[4];
        int lane = tid & 63, wv = tid >> 6;
        if (lane == 0) wsum[wv] = s;
        __syncthreads();
        if (tid == 0) ssum[r] = (wsum[0] + wsum[1]) + (wsum[2] + wsum[3]);
    }
}

// ---- bf16 MFMA wiring probe ------------------------------------------------
// Validates the documented 16x16x32 layout (A: row=l&15, k=8*(l>>4)+j; B
// symmetric) against 8 hypotheses: arg-swap x 4 D-forms. Asymmetric integer
// data -> only the true wiring matches (exact compare). Failure -> fallback.
__device__ unsigned probe_bf16(float* crefF, int l) {
    int i0 = l >> 2, j0 = (l & 3) << 2;
    for (int jj = 0; jj < 4; ++jj) {
        double s = 0.0;
        for (int k = 0; k < 32; ++k) s += probeA(i0, k) * probeB(k, j0 + jj);
        crefF[i0 * 16 + j0 + jj] = (float)s;      // <= 3872, exact in f32
    }
    __syncthreads();
    short8 af, bf;
#pragma unroll
    for (int j = 0; j < 8; ++j) {
        int k = 8 * (l >> 4) + j;
        af[j] = (short)(__float_as_uint((float)probeA(l & 15, k)) >> 16);
        bf[j] = (short)(__float_as_uint((float)probeB(k, l & 15)) >> 16);
    }
    unsigned win = 0xFFFFFFFFu;
    for (int s = 0; s < 2; ++s) {
        f32x4 d = {0.f, 0.f, 0.f, 0.f};
        d = __builtin_amdgcn_mfma_f32_16x16x32_bf16(s ? bf : af, s ? af : bf,
                                                    d, 0, 0, 0);
        for (int dF = 0; dF < 4; ++dF) {
            float err = 0.f;
#pragma unroll
            for (int r = 0; r < 4; ++r) {
                int ii, jj;
                if (dF == 0)      { ii = 4 * (l >> 4) + r; jj = l & 15; }
                else if (dF == 1) { ii = (l >> 4) + 4 * r; jj = l & 15; }
                else if (dF == 2) { jj = 4 * (l >> 4) + r; ii = l & 15; }
                else              { jj = (l >> 4) + 4 * r; ii = l & 15; }
                err = fmaxf(err, fabsf(d[r] - crefF[ii * 16 + jj]));
            }
            for (int off = 1; off < 64; off <<= 1)
                err = fmaxf(err, __shfl_xor(err, off, 64));
            if (err < 0.5f && win == 0xFFFFFFFFu) win = (unsigned)(s * 4 + dF);
        }
    }
    return win;
}

// ---- GEMM h = x . W^T via 3-way bf16 split (6 MFMA products) ---------------
// v18: 64x64 tile, 2 waves k-split even/odd chunks (zero loop barriers --
// R4's proven shape), NO LDS staging: fragments direct-loaded as short8 from
// the bf16 planes (L2/L3-resident). accH = a0b0; accM = a0b1+a1b0+a1b1+
// a0b2+a2b0 (dropped terms <= 2^-27 rel). h error ~ f32-accum (~1e-6) ==
// reference's own f32 einsum error class (validated margin: f64-exact h
// matched ref spikes with absmax=0).
#define MF(a, b, c) __builtin_amdgcn_mfma_f32_16x16x32_bf16((a), (b), (c), 0, 0, 0)

#define SIX_AB                                                        \
    accH[f][g] = MF(aa0, bb0[g], accH[f][g]);                         \
    accM[f][g] = MF(aa0, bb1[g], accM[f][g]);                         \
    accM[f][g] = MF(aa1, bb0[g], accM[f][g]);                         \
    accM[f][g] = MF(aa1, bb1[g], accM[f][g]);                         \
    accM[f][g] = MF(aa0, bb2[g], accM[f][g]);                         \
    accM[f][g] = MF(aa2, bb0[g], accM[f][g]);

#define SIX_BA                                                        \
    accH[f][g] = MF(bb0[g], aa0, accH[f][g]);                         \
    accM[f][g] = MF(bb1[g], aa0, accM[f][g]);                         \
    accM[f][g] = MF(bb0[g], aa1, accM[f][g]);                         \
    accM[f][g] = MF(bb1[g], aa1, accM[f][g]);                         \
    accM[f][g] = MF(bb2[g], aa0, accM[f][g]);                         \
    accM[f][g] = MF(bb0[g], aa2, accM[f][g]);

#define MAINLOOP(SIX)                                                 \
    for (int c = w; c < 64; c += 2) {                                 \
        const int koff = c * 32;                                      \
        short8 bb0[4], bb1[4], bb2[4];                                \
        _Pragma("unroll")                                             \
        for (int g = 0; g < 4; ++g) {                                 \
            const unsigned short* bp = Bbase + (size_t)(16 * g) * N_DIM + koff; \
            bb0[g] = *(const short8*)(bp);                            \
            bb1[g] = *(const short8*)(bp + PLANE);                    \
            bb2[g] = *(const short8*)(bp + 2 * PLANE);                \
        }                                                             \
        _Pragma("unroll")                                             \
        for (int f = 0; f < 4; ++f) {                                 \
            const unsigned short* ap = Abase + (size_t)(16 * f) * N_DIM + koff; \
            short8 aa0 = *(const short8*)(ap);                        \
            short8 aa1 = *(const short8*)(ap + PLANE);                \
            short8 aa2 = *(const short8*)(ap + 2 * PLANE);            \
            _Pragma("unroll")                                         \
            for (int g = 0; g < 4; ++g) { SIX }                       \
        }                                                             \
    }

__global__ __launch_bounds__(128, 2)
void gemm_bf16(const float* __restrict__ x, const float* __restrict__ W,
               float* __restrict__ C, double* __restrict__ psum,
               double* __restrict__ psum2) {
    __shared__ __align__(16) char smem[32768];   // probe Cref, then cbuf
    const int t    = threadIdx.x;
    const int lane = t & 63;
    const int w    = t >> 6;
    const int row0 = blockIdx.y * 64;
    const int col0 = blockIdx.x * 64;
    const int band = blockIdx.y;

    const unsigned win = probe_bf16((float*)smem, lane);
    __syncthreads();
    double* cbuf = (double*)smem;                // 4096 doubles = 32KB

    if (win <= 7u) {
        const int swp = win >> 2, dF = win & 3;
        int iD[4], jD[4];
#pragma unroll
        for (int r = 0; r < 4; ++r) {
            if (dF == 0)      { iD[r] = 4 * (lane >> 4) + r; jD[r] = lane & 15; }
            else if (dF == 1) { iD[r] = (lane >> 4) + 4 * r; jD[r] = lane & 15; }
            else if (dF == 2) { jD[r] = 4 * (lane >> 4) + r; iD[r] = lane & 15; }
            else              { jD[r] = (lane >> 4) + 4 * r; iD[r] = lane & 15; }
        }

        const unsigned short* Abase =
            g_planes + (size_t)(row0 + (lane & 15)) * N_DIM + 8 * (lane >> 4);
        const unsigned short* Bbase =
            g_planes + 3 * PLANE + (size_t)(col0 + (lane & 15)) * N_DIM + 8 * (lane >> 4);

        f32x4 accH[4][4], accM[4][4];
#pragma unroll
        for (int f = 0; f < 4; ++f)
#pragma unroll
            for (int g = 0; g < 4; ++g) {
                accH[f][g] = (f32x4){0.f, 0.f, 0.f, 0.f};
                accM[f][g] = (f32x4){0.f, 0.f, 0.f, 0.f};
            }

        if (!swp) { MAINLOOP(SIX_AB) } else { MAINLOOP(SIX_BA) }

        // epilogue: k-split combine IN-PLACE at scatter position (both waves
        // share the identical lane->(i,j) map), then C store + BN partials.
        __syncthreads();
        if (w == 1) {
#pragma unroll
            for (int f = 0; f < 4; ++f)
#pragma unroll
                for (int g = 0; g < 4; ++g)
#pragma unroll
                    for (int r = 0; r < 4; ++r)
                        cbuf[(16 * f + iD[r]) * 64 + 16 * g + jD[r]] =
                            (double)accH[f][g][r] + (double)accM[f][g][r];
        }
        __syncthreads();
        if (w == 0) {
#pragma unroll
            for (int f = 0; f < 4; ++f)
#pragma unroll
                for (int g = 0; g < 4; ++g)
#pragma unroll
                    for (int r = 0; r < 4; ++r) {
                        int ci = (16 * f + iD[r]) * 64 + 16 * g + jD[r];
                        double vv = (double)accH[f][g][r] + (double)accM[f][g][r]
                                  + cbuf[ci];
                        cbuf[ci] = vv;
                        C[(size_t)(row0 + 16 * f + iD[r]) * N_DIM
                          + col0 + 16 * g + jD[r]] = (float)vv;
                    }
            // column stats over the 64x64 tile (same-wave DS ordering)
            double s = 0.0, q = 0.0;
#pragma unroll
            for (int r = 0; r < 64; ++r) {
                double v = cbuf[r * 64 + lane];
                s += v;
                q = fma(v, v, q);
            }
            psum [band * N_DIM + col0 + lane] = s;
            psum2[band * N_DIM + col0 + lane] = q;
        }
    } else {
        // correctness-only fallback (probe failed): naive f64 dot products
        for (int off = t; off < 64 * 64; off += 128) {
            int rr = off >> 6, cc = off & 63;
            const float* xr = x + (size_t)(row0 + rr) * N_DIM;
            const float* wr = W + (size_t)(col0 + cc) * N_DIM;
            double s = 0.0;
            for (int k = 0; k < N_DIM; ++k)
                s += (double)xr[k] * (double)wr[k];
            C[(size_t)(row0 + rr) * N_DIM + col0 + cc] = (float)s;
        }
        __syncthreads();
        if (t < 64) {
            double s = 0.0, q = 0.0;
            for (int rr = 0; rr < 64; ++rr) {
                double v = (double)C[(size_t)(row0 + rr) * N_DIM + col0 + t];
                s += v;
                q = fma(v, v, q);
            }
            psum [band * N_DIM + col0 + t] = s;
            psum2[band * N_DIM + col0 + t] = q;
        }
    }
}

// ---- fused BN-final + BN-apply + temporal-sum + triple LIF + output -------
__global__ __launch_bounds__(256)
void fused_lif_kernel(const float* __restrict__ x, const float* __restrict__ h,
                      const double* __restrict__ psum, const double* __restrict__ psum2,
                      const float* __restrict__ gamma, const float* __restrict__ beta,
                      const double* __restrict__ ssum, float* __restrict__ out) {
    int idx = blockIdx.x * 256 + threadIdx.x;
    int n = idx & (N_DIM - 1);
    int b = idx >> 11;
    // BN scale/shift for this column
    double s = 0.0, s2 = 0.0;
#pragma unroll
    for (int c = 0; c < 32; ++c) {
        s  += psum [c * N_DIM + n];
        s2 += psum2[c * N_DIM + n];
    }
    double mean = s * (1.0 / 2048.0);
    double var  = s2 * (1.0 / 2048.0) - mean * mean;
    double istd = 1.0 / sqrt(var + 1e-5);
    double sc = istd * (double)gamma[n];
    double sh = (double)beta[n] - mean * sc;
    // temporal sum (ascending t, f64)
    float xv[T_DIM];
    double ts = 0.0;
#pragma unroll
    for (int t = 0; t < T_DIM; ++t) {
        xv[t] = x[(size_t)(t * B_DIM + b) * N_DIM + n];
        ts += (double)xv[t];
    }
    double v1 = 0.0, v2 = 0.0, v3 = 0.0;
#pragma unroll
    for (int t = 0; t < T_DIM; ++t) {
        size_t off = (size_t)(t * B_DIM + b) * N_DIM + n;
        double hv = fma((double)h[off], sc, sh);
        v1 = v1 * 0.5 + hv;
        bool s1 = (v1 >= 1.0); if (s1) v1 = 0.0;
        double in2 = s1 ? ssum[t * B_DIM + b] : 0.0;
        v2 = v2 * 0.5 + in2;
        bool s2b = (v2 >= 1.0); if (s2b) v2 = 0.0;
        double in3 = s1 ? ts : 0.0;
        v3 = v3 * 0.5 + in3;
        bool s3 = (v3 >= 1.0); if (s3) v3 = 0.0;
        out[off] = xv[t] + ((s2b && s3) ? 1.0f : 0.0f);
    }
}

extern "C" void kernel_launch(void* const* d_in, const int* in_sizes, int n_in,
                              void* d_out, int out_size, void* d_ws, size_t ws_size,
                              hipStream_t stream) {
    const float* x     = (const float*)d_in[0];   // [16,128,2048]
    const float* W     = (const float*)d_in[1];   // [2048,2048]
    const float* gamma = (const float*)d_in[2];   // [2048]
    const float* beta  = (const float*)d_in[3];   // [2048]
    float* out = (float*)d_out;

    char* ws = (char*)d_ws;
    float*  h     = (float*)(ws + WS_H);
    double* psum  = (double*)(ws + WS_PSUM);
    double* psum2 = (double*)(ws + WS_PSUM2);
    double* ssum  = (double*)(ws + WS_SSUM);

    split_kernel<<<4096, 256, 0, stream>>>(x, W, ssum);
    gemm_bf16<<<dim3(N_DIM / 64, TB / 64), 128, 0, stream>>>(x, W, h, psum, psum2);
    fused_lif_kernel<<<(B_DIM * N_DIM) / 256, 256, 0, stream>>>(
        x, h, psum, psum2, gamma, beta, ssum, out);
}